// Round 3
// baseline (227.563 us; speedup 1.0000x reference)
//
#include <hip/hip_runtime.h>

#define NLEV 8
#define NK 512
#define ND 64
#define ROWS_BLK 32

// output layout (floats): qsum | indices | loss | probs
#define IDX_OFF   1048576
#define LOSS_OFF  1179648
#define PROBS_OFF 1179664

// ---------------- preprocess: transpose codebook + fp32 squared norms ----------------
__global__ void hrq_pre(const float* __restrict__ emb,
                        float* __restrict__ embT,
                        float* __restrict__ wn2) {
  int t = blockIdx.x * 256 + threadIdx.x;   // [0, 4096)
  if (t >= NLEV * NK) return;
  int h = t >> 9, k = t & (NK - 1);
  const float* wrow = emb + (size_t)(h * NK + k) * ND;
  // 8-accumulator pairwise sum of squares (fp32, no FMA contraction)
  float r8[8];
#pragma unroll
  for (int j = 0; j < 8; ++j) r8[j] = __fmul_rn(wrow[j], wrow[j]);
#pragma unroll
  for (int i = 1; i < 8; ++i)
#pragma unroll
    for (int j = 0; j < 8; ++j)
      r8[j] = __fadd_rn(r8[j], __fmul_rn(wrow[8 * i + j], wrow[8 * i + j]));
  wn2[t] = __fadd_rn(__fadd_rn(__fadd_rn(r8[0], r8[1]), __fadd_rn(r8[2], r8[3])),
                     __fadd_rn(__fadd_rn(r8[4], r8[5]), __fadd_rn(r8[6], r8[7])));
#pragma unroll
  for (int d = 0; d < ND; ++d)
    embT[((size_t)h * ND + d) * NK + k] = wrow[d];
}

// sequential-ascending-k fp32 FMA (BLAS microkernel order), single accumulator
#define FMA_STEP(rr, rv, wa, wb)                    \
  s[rr][0] = fmaf((rv), (wa).x, s[rr][0]);          \
  s[rr][1] = fmaf((rv), (wa).y, s[rr][1]);          \
  s[rr][2] = fmaf((rv), (wa).z, s[rr][2]);          \
  s[rr][3] = fmaf((rv), (wa).w, s[rr][3]);          \
  s[rr][4] = fmaf((rv), (wb).x, s[rr][4]);          \
  s[rr][5] = fmaf((rv), (wb).y, s[rr][5]);          \
  s[rr][6] = fmaf((rv), (wb).z, s[rr][6]);          \
  s[rr][7] = fmaf((rv), (wb).w, s[rr][7]);

// ---------------- main kernel ----------------
__launch_bounds__(256, 2)
__global__ void hrq_main(const float* __restrict__ z,
                         const float* __restrict__ emb,
                         const float* __restrict__ embT,
                         const float* __restrict__ wn2,
                         const int* __restrict__ epoch_p,
                         float* __restrict__ out,
                         float* __restrict__ loss_partial) {
  __shared__ float z_lds[ROWS_BLK][68];
  __shared__ float qs_lds[ROWS_BLK][68];   // quant_sum, fp32 sequential accumulation
  __shared__ float r_lds[ROWS_BLK][68];    // residual, rebuilt each level as fl(z - qs)
  __shared__ float loss_lds[ROWS_BLK];

  const int tid = threadIdx.x;
  const int n0 = blockIdx.x * ROWS_BLK;

  for (int i = tid; i < ROWS_BLK * ND; i += 256) {
    int row = i >> 6, d = i & 63;
    z_lds[row][d] = z[(size_t)(n0 + row) * ND + d];
    qs_lds[row][d] = 0.f;
  }
  __syncthreads();

  const int wid = tid >> 6;
  const int lane = tid & 63;
  const int r0 = wid * 8;

  int ei = *epoch_p;
  float ef = (ei >= 0 && ei < 1000000) ? (float)ei : *(const float*)(const void*)epoch_p;

  float temps[NLEV];
  const double denoms[NLEV] = {10.0, 15.0, 22.5, 33.75, 50.625,
                               75.9375, 113.90625, 170.859375};
#pragma unroll
  for (int h = 0; h < NLEV; ++h) {
    double tv = exp(-(double)ef / denoms[h]);
    temps[h] = (float)(tv > 0.5 ? tv : 0.5);
  }

  float my_loss = 0.f, my_nl = 0.f, my_unprev = 1.f;

#pragma unroll 1
  for (int h = 0; h < NLEV; ++h) {
    const float* wT = embT + (size_t)h * ND * NK;
    const float* wn = wn2 + h * NK;

    // rebuild residual: r = fl(z - quant_sum)  (matches reference exactly)
#pragma unroll
    for (int rr = 0; rr < 8; ++rr)
      r_lds[r0 + rr][lane] = __fsub_rn(z_lds[r0 + rr][lane], qs_lds[r0 + rr][lane]);

    // A = |r|^2 per row (8-acc pairwise; exact order is grid-uniform, any accurate sum ok)
    {
      // compute below after writes are visible (same wave; compiler inserts lgkm waits)
    }
    const int arow = lane >> 3, aj = lane & 7;
    const float* rp = &r_lds[r0 + arow][0];
    float va = rp[aj];
    float accA = __fmul_rn(va, va);
#pragma unroll
    for (int i = 1; i < 8; ++i) {
      float x = rp[8 * i + aj];
      accA = __fadd_rn(accA, __fmul_rn(x, x));
    }
    {
      float o = __shfl_xor(accA, 1); accA = __fadd_rn(accA, o);
      o = __shfl_xor(accA, 2); accA = __fadd_rn(accA, o);
      o = __shfl_xor(accA, 4); accA = __fadd_rn(accA, o);
    }
    // lanes 8*rr..8*rr+7 now hold A of row r0+rr

    float s[8][8];
#pragma unroll
    for (int ii = 0; ii < 8; ++ii)
#pragma unroll
      for (int jj = 0; jj < 8; ++jj) s[ii][jj] = 0.f;

    // C = r.w : fp32 FMA, k ascending, single accumulator per (row, code)
#pragma unroll 2
    for (int d0 = 0; d0 < ND; d0 += 4) {
      float4 w0[4], w1[4];
#pragma unroll
      for (int dd = 0; dd < 4; ++dd) {
        const float* wp = wT + (size_t)(d0 + dd) * NK + 4 * lane;
        w0[dd] = *(const float4*)wp;
        w1[dd] = *(const float4*)(wp + 256);
      }
#pragma unroll
      for (int rr = 0; rr < 8; ++rr) {
        float4 r4 = *(const float4*)&r_lds[r0 + rr][d0];
        FMA_STEP(rr, r4.x, w0[0], w1[0]);
        FMA_STEP(rr, r4.y, w0[1], w1[1]);
        FMA_STEP(rr, r4.z, w0[2], w1[2]);
        FMA_STEP(rr, r4.w, w0[3], w1[3]);
      }
    }

    const float inv_temp = 1.f / temps[h];
    const float4 wnA = *(const float4*)&wn[4 * lane];
    const float4 wnB = *(const float4*)&wn[256 + 4 * lane];
    const float Bl[8] = {wnA.x, wnA.y, wnA.z, wnA.w, wnB.x, wnB.y, wnB.z, wnB.w};

#pragma unroll
    for (int rr = 0; rr < 8; ++rr) {
      const float A = __shfl(accA, 8 * rr);
      // u_k = fl(fl(A + B_k) - fl(2*C_k));  d_k = -u_k. argmax d == argmin u,
      // ties resolved first-index (reference fp32 grid reproduced exactly).
      float u[8];
#pragma unroll
      for (int j = 0; j < 8; ++j)
        u[j] = __fsub_rn(__fadd_rn(A, Bl[j]), __fmul_rn(2.f, s[rr][j]));

      const int c0 = 4 * lane;
      const int codeid[8] = {c0, c0 + 1, c0 + 2, c0 + 3,
                             c0 + 256, c0 + 257, c0 + 258, c0 + 259};
      float m = u[0]; int mi = codeid[0];
#pragma unroll
      for (int j = 1; j < 8; ++j)
        if (u[j] < m) { m = u[j]; mi = codeid[j]; }   // strict: keeps first index
#pragma unroll
      for (int off = 1; off < 64; off <<= 1) {
        float om = __shfl_xor(m, off);
        int oi = __shfl_xor(mi, off);
        if (om < m || (om == m && oi < mi)) { m = om; mi = oi; }
      }

      // t_j = d_j - d_max = u_min - u_j  (<= 0); softmax/KL are tolerance-loose
      float t0 = m - u[0], t1 = m - u[1], t2 = m - u[2], t3 = m - u[3];
      float t4 = m - u[4], t5 = m - u[5], t6 = m - u[6], t7 = m - u[7];

      float ss = t0 + t1 + t2 + t3 + t4 + t5 + t6 + t7;
#pragma unroll
      for (int off = 1; off < 64; off <<= 1) ss += __shfl_xor(ss, off);

      float se = __expf(t0) + __expf(t1) + __expf(t2) + __expf(t3)
               + __expf(t4) + __expf(t5) + __expf(t6) + __expf(t7);
#pragma unroll
      for (int off = 1; off < 64; off <<= 1) se += __shfl_xor(se, off);

      float p0 = __expf(t0 * inv_temp), p1 = __expf(t1 * inv_temp);
      float p2 = __expf(t2 * inv_temp), p3 = __expf(t3 * inv_temp);
      float p4 = __expf(t4 * inv_temp), p5 = __expf(t5 * inv_temp);
      float p6 = __expf(t6 * inv_temp), p7 = __expf(t7 * inv_temp);
      float pden = p0 + p1 + p2 + p3 + p4 + p5 + p6 + p7;
#pragma unroll
      for (int off = 1; off < 64; off <<= 1) pden += __shfl_xor(pden, off);
      const float invden = 1.f / pden;

      const size_t n = (size_t)(n0 + r0 + rr);
      const size_t pb = (n * NLEV + h) * NK;
      *(float4*)&out[PROBS_OFF + pb + 4 * lane] =
          make_float4(p0 * invden, p1 * invden, p2 * invden, p3 * invden);
      *(float4*)&out[PROBS_OFF + pb + 256 + 4 * lane] =
          make_float4(p4 * invden, p5 * invden, p6 * invden, p7 * invden);

      // KL(log_softmax(d), uniform).sum = log(sum exp t) - mean(t) - log K
      const float kl = __logf(se) - ss * (1.f / 512.f) - 6.2383246250395075f;

      // gather chosen codeword (wave-uniform mi), update quant_sum (fp32 sequential)
      const float qv = emb[((size_t)h * NK + mi) * ND + lane];
      qs_lds[r0 + rr][lane] = __fadd_rn(qs_lds[r0 + rr][lane], qv);

      const float un = sqrtf(wn[mi]);
      if (lane == rr) {
        my_loss = fmaf(kl, 0.001f, my_loss);
        if (h > 0) {
          float t2v = fmaxf(un / my_unprev * 1.5f, 1.f) - 1.f;
          my_nl = fmaf(t2v, t2v, my_nl);
        }
        my_unprev = un;
        out[IDX_OFF + n * NLEV + h] = (float)mi;
      }
    }
  }

  if (lane < 8) loss_lds[r0 + lane] = my_loss + my_nl * (0.1f / 7.f);
  __syncthreads();
  if (tid == 0) {
    float acc = 0.f;
#pragma unroll 1
    for (int i = 0; i < ROWS_BLK; ++i) acc += loss_lds[i];
    loss_partial[blockIdx.x] = acc;
  }

  // qsum transposed write: out[b, d, y, x]; block covers fixed (b, y), x = row
  const int b = n0 >> 10;
  const int y = (n0 >> 5) & 31;
  float* qbase = out + (size_t)b * 65536 + (size_t)y * 32;
  for (int i = tid; i < ND * ROWS_BLK; i += 256) {
    int d = i >> 5, x = i & 31;
    qbase[(size_t)d * 1024 + x] = qs_lds[x][d];
  }
}

// ---------------- loss finalize ----------------
__global__ void hrq_loss(const float* __restrict__ partial, float* __restrict__ out_loss) {
  int lane = threadIdx.x;
  float v = (lane < 32) ? partial[blockIdx.x * 32 + lane] : 0.f;
#pragma unroll
  for (int off = 1; off < 64; off <<= 1) v += __shfl_xor(v, off);
  if (lane == 0) out_loss[blockIdx.x] = v * (1.f / 1024.f);
}

extern "C" void kernel_launch(void* const* d_in, const int* in_sizes, int n_in,
                              void* d_out, int out_size, void* d_ws, size_t ws_size,
                              hipStream_t stream) {
  const float* z   = (const float*)d_in[0];
  const float* emb = (const float*)d_in[1];
  const int* epoch = (const int*)d_in[2];
  float* out = (float*)d_out;

  float* embT    = (float*)d_ws;                    // 8*64*512 floats = 512 KB
  float* wn2     = embT + NLEV * ND * NK;           // 8*512 floats
  float* partial = wn2 + NLEV * NK;                 // 512 floats

  const int nrows = in_sizes[0] / ND;               // 16384
  const int nblocks = nrows / ROWS_BLK;             // 512

  hrq_pre<<<16, 256, 0, stream>>>(emb, embT, wn2);
  hrq_main<<<nblocks, 256, 0, stream>>>(z, emb, embT, wn2, epoch, out, partial);
  hrq_loss<<<nrows / 1024, 64, 0, stream>>>(partial, out + LOSS_OFF);
}

// Round 4
// 219.565 us; speedup vs baseline: 1.0364x; 1.0364x over previous
//
#include <hip/hip_runtime.h>

#define NLEV 8
#define NK 512
#define ND 64
#define ROWS_BLK 32
#define NTHR 512

// output layout (floats): qsum | indices | loss | probs
#define IDX_OFF   1048576
#define LOSS_OFF  1179648
#define PROBS_OFF 1179664

// ---------------- preprocess: transpose codebook + fp32 squared norms ----------------
// (op order for wn2 must stay bit-identical to the passing R3 version)
__global__ void hrq_pre(const float* __restrict__ emb,
                        float* __restrict__ embT,
                        float* __restrict__ wn2) {
  int t = blockIdx.x * 256 + threadIdx.x;   // [0, 4096)
  if (t >= NLEV * NK) return;
  int h = t >> 9, k = t & (NK - 1);
  const float* wrow = emb + (size_t)(h * NK + k) * ND;
  float r8[8];
#pragma unroll
  for (int j = 0; j < 8; ++j) r8[j] = __fmul_rn(wrow[j], wrow[j]);
#pragma unroll
  for (int i = 1; i < 8; ++i)
#pragma unroll
    for (int j = 0; j < 8; ++j)
      r8[j] = __fadd_rn(r8[j], __fmul_rn(wrow[8 * i + j], wrow[8 * i + j]));
  wn2[t] = __fadd_rn(__fadd_rn(__fadd_rn(r8[0], r8[1]), __fadd_rn(r8[2], r8[3])),
                     __fadd_rn(__fadd_rn(r8[4], r8[5]), __fadd_rn(r8[6], r8[7])));
#pragma unroll
  for (int d = 0; d < ND; ++d)
    embT[((size_t)h * ND + d) * NK + k] = wrow[d];
}

// sequential-ascending-k fp32 FMA, single accumulator per (row, code)
#define FMA_STEP(rr, rv, wa, wb)                    \
  s[rr][0] = fmaf((rv), (wa).x, s[rr][0]);          \
  s[rr][1] = fmaf((rv), (wa).y, s[rr][1]);          \
  s[rr][2] = fmaf((rv), (wa).z, s[rr][2]);          \
  s[rr][3] = fmaf((rv), (wa).w, s[rr][3]);          \
  s[rr][4] = fmaf((rv), (wb).x, s[rr][4]);          \
  s[rr][5] = fmaf((rv), (wb).y, s[rr][5]);          \
  s[rr][6] = fmaf((rv), (wb).z, s[rr][6]);          \
  s[rr][7] = fmaf((rv), (wb).w, s[rr][7]);

// ---------------- main kernel: 512 thr (8 waves x 4 rows), LDS-staged codebook ----------------
__launch_bounds__(NTHR, 4)
__global__ void hrq_main(const float* __restrict__ z,
                         const float* __restrict__ emb,
                         const float* __restrict__ embT,
                         const float* __restrict__ wn2,
                         const int* __restrict__ epoch_p,
                         float* __restrict__ out,
                         float* __restrict__ loss_partial) {
  __shared__ float z_lds[ROWS_BLK][68];
  __shared__ float qs_lds[ROWS_BLK][68];   // quant_sum, fp32 sequential accumulation
  __shared__ float r_lds[ROWS_BLK][68];    // residual, rebuilt each level as fl(z - qs)
  __shared__ float wbuf[16][NK];           // staged codebook dim-chunk (32 KB)
  __shared__ float loss_lds[ROWS_BLK];

  const int tid = threadIdx.x;
  const int n0 = blockIdx.x * ROWS_BLK;

  for (int i = tid; i < ROWS_BLK * ND; i += NTHR) {
    int row = i >> 6, d = i & 63;
    z_lds[row][d] = z[(size_t)(n0 + row) * ND + d];
    qs_lds[row][d] = 0.f;
  }
  __syncthreads();

  const int wid = tid >> 6;
  const int lane = tid & 63;
  const int r0 = wid * 4;                  // 4 rows per wave

  int ei = *epoch_p;
  float ef = (ei >= 0 && ei < 1000000) ? (float)ei : *(const float*)(const void*)epoch_p;

  float temps[NLEV];
  const double denoms[NLEV] = {10.0, 15.0, 22.5, 33.75, 50.625,
                               75.9375, 113.90625, 170.859375};
#pragma unroll
  for (int h = 0; h < NLEV; ++h) {
    double tv = exp(-(double)ef / denoms[h]);
    temps[h] = (float)(tv > 0.5 ? tv : 0.5);
  }

  float my_loss = 0.f, my_nl = 0.f, my_unprev = 1.f;

#pragma unroll 1
  for (int h = 0; h < NLEV; ++h) {
    const float* wn = wn2 + h * NK;

    // rebuild residual: r = fl(z - quant_sum)  (own-wave rows only)
#pragma unroll
    for (int rr = 0; rr < 4; ++rr)
      r_lds[r0 + rr][lane] = __fsub_rn(z_lds[r0 + rr][lane], qs_lds[r0 + rr][lane]);

    // A = |r|^2 per row — EXACT op order of the passing R3 kernel:
    // 8 lanes per row, dims {aj, aj+8i}, then xor 1,2,4 reduce.
    const int arow = (lane >> 3) & 3, aj = lane & 7;
    const float* rp = &r_lds[r0 + arow][0];
    float va = rp[aj];
    float accA = __fmul_rn(va, va);
#pragma unroll
    for (int i = 1; i < 8; ++i) {
      float x = rp[8 * i + aj];
      accA = __fadd_rn(accA, __fmul_rn(x, x));
    }
    {
      float o = __shfl_xor(accA, 1); accA = __fadd_rn(accA, o);
      o = __shfl_xor(accA, 2); accA = __fadd_rn(accA, o);
      o = __shfl_xor(accA, 4); accA = __fadd_rn(accA, o);
    }

    float s[4][8];
#pragma unroll
    for (int ii = 0; ii < 4; ++ii)
#pragma unroll
      for (int jj = 0; jj < 8; ++jj) s[ii][jj] = 0.f;

    // C = r.w : dims staged in LDS 16 at a time, k ascending, single accumulator
#pragma unroll 1
    for (int chunk = 0; chunk < 4; ++chunk) {
      __syncthreads();   // all waves done reading previous chunk
      {
        const float4* src = (const float4*)(embT + (size_t)h * (ND * NK) + chunk * (16 * NK));
        float4* dst = (float4*)&wbuf[0][0];
#pragma unroll
        for (int i = 0; i < 4; ++i) dst[i * NTHR + tid] = src[i * NTHR + tid];
      }
      __syncthreads();   // chunk staged

#pragma unroll 2
      for (int dd0 = 0; dd0 < 16; dd0 += 4) {
        float4 w0[4], w1[4];
#pragma unroll
        for (int dd = 0; dd < 4; ++dd) {
          w0[dd] = *(const float4*)&wbuf[dd0 + dd][4 * lane];
          w1[dd] = *(const float4*)&wbuf[dd0 + dd][256 + 4 * lane];
        }
#pragma unroll
        for (int rr = 0; rr < 4; ++rr) {
          float4 r4 = *(const float4*)&r_lds[r0 + rr][chunk * 16 + dd0];
          FMA_STEP(rr, r4.x, w0[0], w1[0]);
          FMA_STEP(rr, r4.y, w0[1], w1[1]);
          FMA_STEP(rr, r4.z, w0[2], w1[2]);
          FMA_STEP(rr, r4.w, w0[3], w1[3]);
        }
      }
    }

    const float inv_temp = 1.f / temps[h];
    const float4 wnA = *(const float4*)&wn[4 * lane];
    const float4 wnB = *(const float4*)&wn[256 + 4 * lane];
    const float Bl[8] = {wnA.x, wnA.y, wnA.z, wnA.w, wnB.x, wnB.y, wnB.z, wnB.w};

#pragma unroll
    for (int rr = 0; rr < 4; ++rr) {
      const float A = __shfl(accA, 8 * rr);
      // u_k = fl(fl(A + B_k) - fl(2*C_k)); argmax d == argmin u, first-index ties
      float u[8];
#pragma unroll
      for (int j = 0; j < 8; ++j)
        u[j] = __fsub_rn(__fadd_rn(A, Bl[j]), __fmul_rn(2.f, s[rr][j]));

      const int c0 = 4 * lane;
      const int codeid[8] = {c0, c0 + 1, c0 + 2, c0 + 3,
                             c0 + 256, c0 + 257, c0 + 258, c0 + 259};
      float m = u[0]; int mi = codeid[0];
#pragma unroll
      for (int j = 1; j < 8; ++j)
        if (u[j] < m) { m = u[j]; mi = codeid[j]; }
#pragma unroll
      for (int off = 1; off < 64; off <<= 1) {
        float om = __shfl_xor(m, off);
        int oi = __shfl_xor(mi, off);
        if (om < m || (om == m && oi < mi)) { m = om; mi = oi; }
      }

      float t0 = m - u[0], t1 = m - u[1], t2 = m - u[2], t3 = m - u[3];
      float t4 = m - u[4], t5 = m - u[5], t6 = m - u[6], t7 = m - u[7];

      float ss = t0 + t1 + t2 + t3 + t4 + t5 + t6 + t7;
#pragma unroll
      for (int off = 1; off < 64; off <<= 1) ss += __shfl_xor(ss, off);

      float se = __expf(t0) + __expf(t1) + __expf(t2) + __expf(t3)
               + __expf(t4) + __expf(t5) + __expf(t6) + __expf(t7);
#pragma unroll
      for (int off = 1; off < 64; off <<= 1) se += __shfl_xor(se, off);

      float p0 = __expf(t0 * inv_temp), p1 = __expf(t1 * inv_temp);
      float p2 = __expf(t2 * inv_temp), p3 = __expf(t3 * inv_temp);
      float p4 = __expf(t4 * inv_temp), p5 = __expf(t5 * inv_temp);
      float p6 = __expf(t6 * inv_temp), p7 = __expf(t7 * inv_temp);
      float pden = p0 + p1 + p2 + p3 + p4 + p5 + p6 + p7;
#pragma unroll
      for (int off = 1; off < 64; off <<= 1) pden += __shfl_xor(pden, off);
      const float invden = 1.f / pden;

      const size_t n = (size_t)(n0 + r0 + rr);
      const size_t pb = (n * NLEV + h) * NK;
      *(float4*)&out[PROBS_OFF + pb + 4 * lane] =
          make_float4(p0 * invden, p1 * invden, p2 * invden, p3 * invden);
      *(float4*)&out[PROBS_OFF + pb + 256 + 4 * lane] =
          make_float4(p4 * invden, p5 * invden, p6 * invden, p7 * invden);

      const float kl = __logf(se) - ss * (1.f / 512.f) - 6.2383246250395075f;

      const float qv = emb[((size_t)h * NK + mi) * ND + lane];
      qs_lds[r0 + rr][lane] = __fadd_rn(qs_lds[r0 + rr][lane], qv);

      const float un = sqrtf(wn[mi]);
      if (lane == rr) {
        my_loss = fmaf(kl, 0.001f, my_loss);
        if (h > 0) {
          float t2v = fmaxf(un / my_unprev * 1.5f, 1.f) - 1.f;
          my_nl = fmaf(t2v, t2v, my_nl);
        }
        my_unprev = un;
        out[IDX_OFF + n * NLEV + h] = (float)mi;
      }
    }
  }

  if (lane < 4) loss_lds[r0 + lane] = my_loss + my_nl * (0.1f / 7.f);
  __syncthreads();
  if (tid == 0) {
    float acc = 0.f;
#pragma unroll 1
    for (int i = 0; i < ROWS_BLK; ++i) acc += loss_lds[i];
    loss_partial[blockIdx.x] = acc;
  }

  // qsum transposed write: out[b, d, y, x]; block covers fixed (b, y), x = row
  const int b = n0 >> 10;
  const int y = (n0 >> 5) & 31;
  float* qbase = out + (size_t)b * 65536 + (size_t)y * 32;
  for (int i = tid; i < ND * ROWS_BLK; i += NTHR) {
    int d = i >> 5, x = i & 31;
    qbase[(size_t)d * 1024 + x] = qs_lds[x][d];
  }
}

// ---------------- loss finalize ----------------
__global__ void hrq_loss(const float* __restrict__ partial, float* __restrict__ out_loss) {
  int lane = threadIdx.x;
  float v = (lane < 32) ? partial[blockIdx.x * 32 + lane] : 0.f;
#pragma unroll
  for (int off = 1; off < 64; off <<= 1) v += __shfl_xor(v, off);
  if (lane == 0) out_loss[blockIdx.x] = v * (1.f / 1024.f);
}

extern "C" void kernel_launch(void* const* d_in, const int* in_sizes, int n_in,
                              void* d_out, int out_size, void* d_ws, size_t ws_size,
                              hipStream_t stream) {
  const float* z   = (const float*)d_in[0];
  const float* emb = (const float*)d_in[1];
  const int* epoch = (const int*)d_in[2];
  float* out = (float*)d_out;

  float* embT    = (float*)d_ws;                    // 8*64*512 floats = 512 KB
  float* wn2     = embT + NLEV * ND * NK;           // 8*512 floats
  float* partial = wn2 + NLEV * NK;                 // 512 floats

  const int nrows = in_sizes[0] / ND;               // 16384
  const int nblocks = nrows / ROWS_BLK;             // 512

  hrq_pre<<<16, 256, 0, stream>>>(emb, embT, wn2);
  hrq_main<<<nblocks, NTHR, 0, stream>>>(z, emb, embT, wn2, epoch, out, partial);
  hrq_loss<<<nrows / 1024, 64, 0, stream>>>(partial, out + LOSS_OFF);
}